// Round 6
// baseline (99.539 us; speedup 1.0000x reference)
//
#include <hip/hip_runtime.h>
#include <hip/hip_bf16.h>

#define NN    4096
#define KNEI  16
#define QPW   4              // query nodes per wave
#define WPB   16             // waves per block
#define BLOCK (WPB * 64)
#define QPB   (WPB * QPW)    // 64 queries per block
#define BIGF  3.0e38f

// surrogate score: larger == closer.  pts[j] = (x, y, z, -n2/2)
__device__ __forceinline__ float score_calc(const float4 P, float xi, float yi,
                                            float zi, int j, int iLoc)
{
    float s = fmaf(P.x, xi, fmaf(P.y, yi, fmaf(P.z, zi, P.w)));
    return (j == iLoc) ? -1.0e30f : s;
}

// Wave-wide argmax of (v, idx), ties -> lowest idx (matches stable top_k).
__device__ __forceinline__ void wave_argmax(float v, int idx,
                                            float& m, int& midx, int& w)
{
    float r = v;
    #pragma unroll
    for (int off = 32; off >= 1; off >>= 1) r = fmaxf(r, __shfl_xor(r, off));
    unsigned long long msk = __ballot(v == r);
    if (__popcll(msk) > 1) {                      // rare exact tie: lowest index
        int ci = (v == r) ? idx : 0x7fffffff;
        #pragma unroll
        for (int off = 32; off >= 1; off >>= 1) ci = min(ci, __shfl_xor(ci, off));
        midx = ci;
        unsigned long long m2 = __ballot(v == r && idx == ci);
        w = __ffsll(m2) - 1;
    } else {
        w = __ffsll(msk) - 1;
        midx = __builtin_amdgcn_readlane(idx, w);
    }
    m = r;
}

// 16 extractions with lazy replay; lane (teamBase+r) receives edge r's index.
__device__ __forceinline__ void extract16(float b_sc, int b_idx, float s_sc, int s_idx,
                                          float xi, float yi, float zi, int qLoc,
                                          int teamBase, const float4* pts,
                                          int lane, int& selIdx)
{
    unsigned long long used = 0ull;   // bit t => candidate (lane + 64t) consumed
    #pragma unroll 1
    for (int r = 0; r < KNEI; ++r) {
        float m; int midx, w;
        wave_argmax(b_sc, b_idx, m, midx, w);
        if (lane == teamBase + r) selIdx = midx;

        bool needReplay = (__builtin_amdgcn_readlane(s_idx, w) == -1);
        if (lane == w) {                               // promote second -> best
            used |= 1ull << (b_idx >> 6);
            b_sc = s_sc;  b_idx = s_idx;
            s_sc = -BIGF; s_idx = -1;
        }
        if (needReplay) {                              // uniform rare branch:
            int j2 = w + (lane << 6);                  // wave rescans lane w's 64
            float scr = score_calc(pts[j2], xi, yi, zi, j2, qLoc);
            unsigned lo = (unsigned)__builtin_amdgcn_readlane((int)(used & 0xffffffffull), w);
            unsigned hi = (unsigned)__builtin_amdgcn_readlane((int)(used >> 32), w);
            unsigned long long uw = ((unsigned long long)hi << 32) | lo;
            if ((uw >> lane) & 1ull) scr = -BIGF;
            float m2; int i2, w2;
            wave_argmax(scr, j2, m2, i2, w2);
            if (lane == w) { b_sc = m2; b_idx = i2; }  // refill best only
        }
    }
}

#define LADDER(d, b, bi, s, si)                                   \
    {  bool gtb = (d) > (b); bool gts = (d) > (s);                \
       float m1_ = fminf((d), (b));                               \
       (s)  = fmaxf((s), m1_);                                    \
       (si) = gtb ? (bi) : (gts ? j : (si));                      \
       (b)  = fmaxf((b), (d));                                    \
       (bi) = gtb ? j : (bi); }

__global__ __launch_bounds__(BLOCK, 8)
void protein_enc_kernel(const float* __restrict__ coords,
                        const int*   __restrict__ atypes,
                        const int*   __restrict__ rtypes,
                        const float* __restrict__ tpw,
                        const float* __restrict__ aemb,
                        const float* __restrict__ remb,
                        float* __restrict__ out)
{
    __shared__ float4 pts[NN];      // x, y, z, -n2/2
    __shared__ float  sW[8 * 32];

    const int tid  = threadIdx.x;
    const int lane = tid & 63;
    const int wv   = tid >> 6;
    const int bpb  = NN / QPB;
    const int batch    = blockIdx.x / bpb;
    const int nodeBase = (blockIdx.x % bpb) * QPB;

    const float* cb = coords + (size_t)batch * NN * 3;

    // ---- stage 4 points per thread via 3 float4 loads ----
    {
        const float4* c4 = (const float4*)cb;
        float4 a = c4[3*tid], b = c4[3*tid+1], c = c4[3*tid+2];
        float x, y, z;
        x = a.x; y = a.y; z = a.z;
        pts[4*tid+0] = make_float4(x, y, z, -0.5f * (x*x + y*y + z*z));
        x = a.w; y = b.x; z = b.y;
        pts[4*tid+1] = make_float4(x, y, z, -0.5f * (x*x + y*y + z*z));
        x = b.z; y = b.w; z = c.x;
        pts[4*tid+2] = make_float4(x, y, z, -0.5f * (x*x + y*y + z*z));
        x = c.y; y = c.z; z = c.w;
        pts[4*tid+3] = make_float4(x, y, z, -0.5f * (x*x + y*y + z*z));
    }
    if (tid < 256) sW[tid] = tpw[tid];
    __syncthreads();

    const int q0 = nodeBase + wv * QPW;          // this wave's 4 query nodes
    const float4 P0 = pts[q0],   P1 = pts[q0+1];
    const float4 P2 = pts[q0+2], P3 = pts[q0+3];
    const float x0 = P0.x, y0 = P0.y, z0 = P0.z;
    const float x1 = P1.x, y1 = P1.y, z1 = P1.z;
    const float x2 = P2.x, y2 = P2.y, z2 = P2.z;
    const float x3 = P3.x, y3 = P3.y, z3 = P3.z;

    // ---- phase 1: 4 branchless per-lane top-2 ladders, one LDS read ----
    float b0 = -BIGF, s0 = -BIGF, b1 = -BIGF, s1 = -BIGF;
    float b2 = -BIGF, s2 = -BIGF, b3 = -BIGF, s3 = -BIGF;
    int bi0 = -1, si0 = -1, bi1 = -1, si1 = -1;
    int bi2 = -1, si2 = -1, bi3 = -1, si3 = -1;

    #pragma unroll 4
    for (int c = 0; c < NN / 64; ++c) {
        int j = lane + (c << 6);
        float4 P = pts[j];
        float d0 = fmaf(P.x, x0, fmaf(P.y, y0, fmaf(P.z, z0, P.w)));
        float d1 = fmaf(P.x, x1, fmaf(P.y, y1, fmaf(P.z, z1, P.w)));
        float d2 = fmaf(P.x, x2, fmaf(P.y, y2, fmaf(P.z, z2, P.w)));
        float d3 = fmaf(P.x, x3, fmaf(P.y, y3, fmaf(P.z, z3, P.w)));
        LADDER(d0, b0, bi0, s0, si0)
        LADDER(d1, b1, bi1, s1, si1)
        LADDER(d2, b2, bi2, s2, si2)
        LADDER(d3, b3, bi3, s3, si3)
    }

    // self wins its own column: demote it (per query)
    if (lane == ((q0  ) & 63) && bi0 == q0  ) { b0 = s0; bi0 = si0; s0 = -BIGF; si0 = -1; }
    if (lane == ((q0+1) & 63) && bi1 == q0+1) { b1 = s1; bi1 = si1; s1 = -BIGF; si1 = -1; }
    if (lane == ((q0+2) & 63) && bi2 == q0+2) { b2 = s2; bi2 = si2; s2 = -BIGF; si2 = -1; }
    if (lane == ((q0+3) & 63) && bi3 == q0+3) { b3 = s3; bi3 = si3; s3 = -BIGF; si3 = -1; }

    // ---- phase 2: 4 sequential extraction passes ----
    int selIdx = 0;                     // lane 16*q + r owns edge r of query q
    extract16(b0, bi0, s0, si0, x0, y0, z0, q0,   0,  pts, lane, selIdx);
    extract16(b1, bi1, s1, si1, x1, y1, z1, q0+1, 16, pts, lane, selIdx);
    extract16(b2, bi2, s2, si2, x2, y2, z2, q0+2, 32, pts, lane, selIdx);
    extract16(b3, bi3, s3, si3, x3, y3, z3, q0+3, 48, pts, lane, selIdx);

    // ---- epilogue: each lane computes its edge's 24 S-components once ----
    const int eq = lane >> 4;
    float xq = (eq & 2) ? ((eq & 1) ? x3 : x2) : ((eq & 1) ? x1 : x0);
    float yq = (eq & 2) ? ((eq & 1) ? y3 : y2) : ((eq & 1) ? y1 : y0);
    float zq = (eq & 2) ? ((eq & 1) ? z3 : z2) : ((eq & 1) ? z1 : z0);

    float4 P = pts[selIdx];
    float rx = P.x - xq, ry = P.y - yq, rz = P.z - zq;   // sender - receiver
    float dist = sqrtf(rx*rx + ry*ry + rz*rz);
    float inv  = 1.0f / (dist + 1e-8f);
    float hx = rx * inv, hy = ry * inv, hz = rz * inv;
    float cu = fminf(dist / 10.0f, 1.0f);
    float gg[8], ssum = 0.0f;
    #pragma unroll
    for (int v = 0; v < 8; ++v) {
        float d = cu - (float)v * (1.0f / 7.0f);
        gg[v] = expf(d * d * -32.0f);
        ssum += gg[v];
    }
    float is = 1.0f / ssum;
    float S[24];
    #pragma unroll
    for (int v = 0; v < 8; ++v) {
        float rbv = gg[v] * is;
        S[3*v]   = rbv * hx;
        S[3*v+1] = rbv * hy;
        S[3*v+2] = rbv * hz;
    }
    // sum the 16 edges within each query's 16-lane group
    #pragma unroll
    for (int off = 1; off <= 8; off <<= 1) {
        #pragma unroll
        for (int t = 0; t < 24; ++t) S[t] += __shfl_xor(S[t], off);
    }

    // W column held once in registers, reused for all 4 queries
    float wcol[8];
    #pragma unroll
    for (int v = 0; v < 8; ++v) wcol[v] = sW[32*v + (lane & 31)];

    const float scale = 0.036084391824351613f;   // 1/(16*sqrt(3))
    const float4 z4 = make_float4(0.f, 0.f, 0.f, 0.f);

    #pragma unroll
    for (int q = 0; q < QPW; ++q) {
        const int gq = batch * NN + q0 + q;
        float sg[24];
        #pragma unroll
        for (int t = 0; t < 24; ++t)
            sg[t] = __int_as_float(
                __builtin_amdgcn_readlane(__float_as_int(S[t]), 16 * q));

        float* onode = out + (size_t)gq * 464;
        float4* o4 = (float4*)onode;
        if (lane < 16)       o4[lane] = z4;          // ch 0..63
        else if (lane < 36)  o4[lane + 24] = z4;     // ch 160..239

        if (lane < 32) {
            float a0 = 0.f, a1 = 0.f, a2 = 0.f;
            #pragma unroll
            for (int v = 0; v < 8; ++v) {
                a0 = fmaf(wcol[v], sg[3*v],   a0);
                a1 = fmaf(wcol[v], sg[3*v+1], a1);
                a2 = fmaf(wcol[v], sg[3*v+2], a2);
            }
            onode[64 + 3*lane]     = a0 * scale;
            onode[64 + 3*lane + 1] = a1 * scale;
            onode[64 + 3*lane + 2] = a2 * scale;
        }

        const int at = atypes[gq];
        const int rt = rtypes[gq];
        if (lane < 56) {
            float4 v = (lane < 28)
                ? ((const float4*)(aemb + 112*at))[lane]
                : ((const float4*)(remb + 112*rt))[lane - 28];
            o4[60 + lane] = v;
        }
    }
}

extern "C" void kernel_launch(void* const* d_in, const int* in_sizes, int n_in,
                              void* d_out, int out_size, void* d_ws, size_t ws_size,
                              hipStream_t stream)
{
    const float* coords = (const float*)d_in[0];
    const int*   at     = (const int*)  d_in[1];
    const int*   rt     = (const int*)  d_in[2];
    const float* tpw    = (const float*)d_in[3];
    const float* ae     = (const float*)d_in[4];
    const float* re     = (const float*)d_in[5];
    float* out = (float*)d_out;

    const int B = in_sizes[1] / NN;                  // 8
    dim3 grid(B * (NN / QPB));
    protein_enc_kernel<<<grid, BLOCK, 0, stream>>>(coords, at, rt, tpw, ae, re, out);
}

// Round 7
// 90.603 us; speedup vs baseline: 1.0986x; 1.0986x over previous
//
#include <hip/hip_runtime.h>
#include <hip/hip_bf16.h>

#define NN    4096
#define KNEI  16
#define QPW   4              // query nodes per wave
#define WPB   16             // waves per block
#define BLOCK (WPB * 64)
#define QPB   (WPB * QPW)    // 64 queries per block
#define BIGF  3.0e38f

// ---------------- DPP wave reductions (VALU pipe, no LDS) ----------------
// row_shr:n = 0x110|n ; row_bcast15 = 0x142 ; row_bcast31 = 0x143

__device__ __forceinline__ float wave_max_dpp(float v)   // lane 63 -> wave max
{
    float f = v;
#define STEPX(CTRL)                                                          \
    { int s_ = __builtin_amdgcn_update_dpp(__float_as_int(f),                \
               __float_as_int(f), (CTRL), 0xF, 0xF, false);                  \
      f = fmaxf(f, __int_as_float(s_)); }
    STEPX(0x111) STEPX(0x112) STEPX(0x114) STEPX(0x118) STEPX(0x142) STEPX(0x143)
#undef STEPX
    return f;
}

__device__ __forceinline__ int wave_min_i32_dpp(int v)   // lane 63 -> wave min
{
    int f = v;
#define STEPM(CTRL)                                                          \
    { int s_ = __builtin_amdgcn_update_dpp(f, f, (CTRL), 0xF, 0xF, false);   \
      f = min(f, s_); }
    STEPM(0x111) STEPM(0x112) STEPM(0x114) STEPM(0x118) STEPM(0x142) STEPM(0x143)
#undef STEPM
    return f;
}

__device__ __forceinline__ float row16_sum_dpp(float v)  // lane 16r+15 -> row sum
{
    float f = v;
#define STEPA(CTRL)                                                          \
    { int s_ = __builtin_amdgcn_update_dpp(0, __float_as_int(f),             \
               (CTRL), 0xF, 0xF, true);                                      \
      f += __int_as_float(s_); }
    STEPA(0x111) STEPA(0x112) STEPA(0x114) STEPA(0x118)
#undef STEPA
    return f;
}

// surrogate score: larger == closer.  pts[j] = (x, y, z, -n2/2)
__device__ __forceinline__ float score_calc(const float4 P, float xi, float yi,
                                            float zi, int j, int iLoc)
{
    float s = fmaf(P.x, xi, fmaf(P.y, yi, fmaf(P.z, zi, P.w)));
    return (j == iLoc) ? -1.0e30f : s;
}

// Wave-wide argmax of (v, idx), ties -> lowest idx (matches stable top_k).
__device__ __forceinline__ void wave_argmax(float v, int idx,
                                            float& m, int& midx, int& w)
{
    float f = wave_max_dpp(v);
    float M = __int_as_float(__builtin_amdgcn_readlane(__float_as_int(f), 63));
    unsigned long long msk = __ballot(v == M);
    if (__popcll(msk) > 1) {                      // rare exact tie: lowest index
        int ci = (v == M) ? idx : 0x7fffffff;
        ci = wave_min_i32_dpp(ci);
        ci = __builtin_amdgcn_readlane(ci, 63);
        midx = ci;
        unsigned long long m2 = __ballot(v == M && idx == ci);
        w = __ffsll(m2) - 1;
    } else {
        w = __ffsll(msk) - 1;
        midx = __builtin_amdgcn_readlane(idx, w);
    }
    m = M;
}

// 16 extractions with lazy replay; lane (teamBase+r) receives edge r's index.
__device__ __forceinline__ void extract16(float b_sc, int b_idx, float s_sc, int s_idx,
                                          float xi, float yi, float zi, int qLoc,
                                          int teamBase, const float4* pts,
                                          int lane, int& selIdx)
{
    unsigned long long used = 0ull;   // bit t => candidate (lane + 64t) consumed
    #pragma unroll 1
    for (int r = 0; r < KNEI; ++r) {
        float m; int midx, w;
        wave_argmax(b_sc, b_idx, m, midx, w);
        if (lane == teamBase + r) selIdx = midx;

        bool needReplay = (__builtin_amdgcn_readlane(s_idx, w) == -1);
        if (lane == w) {                               // promote second -> best
            used |= 1ull << (b_idx >> 6);
            b_sc = s_sc;  b_idx = s_idx;
            s_sc = -BIGF; s_idx = -1;
        }
        if (needReplay) {                              // uniform rare branch:
            int j2 = w + (lane << 6);                  // wave rescans lane w's 64
            float scr = score_calc(pts[j2], xi, yi, zi, j2, qLoc);
            unsigned lo = (unsigned)__builtin_amdgcn_readlane((int)(used & 0xffffffffull), w);
            unsigned hi = (unsigned)__builtin_amdgcn_readlane((int)(used >> 32), w);
            unsigned long long uw = ((unsigned long long)hi << 32) | lo;
            if ((uw >> lane) & 1ull) scr = -BIGF;
            float m2; int i2, w2;
            wave_argmax(scr, j2, m2, i2, w2);
            if (lane == w) { b_sc = m2; b_idx = i2; }  // refill best only
        }
    }
}

// s_new = median(d, s_old, b_old); strict-> keeps stable ordering on ties
#define LADDER(d, b, bi, s, si)                                   \
    {  bool gtb = (d) > (b); bool gts = (d) > (s);                \
       (s)  = __builtin_amdgcn_fmed3f((d), (s), (b));             \
       (si) = gtb ? (bi) : (gts ? j : (si));                      \
       (b)  = fmaxf((b), (d));                                    \
       (bi) = gtb ? j : (bi); }

__global__ __launch_bounds__(BLOCK, 8)
void protein_enc_kernel(const float* __restrict__ coords,
                        const int*   __restrict__ atypes,
                        const int*   __restrict__ rtypes,
                        const float* __restrict__ tpw,
                        const float* __restrict__ aemb,
                        const float* __restrict__ remb,
                        float* __restrict__ out)
{
    __shared__ float4 pts[NN];      // x, y, z, -n2/2
    __shared__ float  sW[8 * 32];

    const int tid  = threadIdx.x;
    const int lane = tid & 63;
    const int wv   = tid >> 6;
    const int bpb  = NN / QPB;
    const int batch    = blockIdx.x / bpb;
    const int nodeBase = (blockIdx.x % bpb) * QPB;

    const float* cb = coords + (size_t)batch * NN * 3;

    // ---- stage 4 points per thread via 3 float4 loads ----
    {
        const float4* c4 = (const float4*)cb;
        float4 a = c4[3*tid], b = c4[3*tid+1], c = c4[3*tid+2];
        float x, y, z;
        x = a.x; y = a.y; z = a.z;
        pts[4*tid+0] = make_float4(x, y, z, -0.5f * (x*x + y*y + z*z));
        x = a.w; y = b.x; z = b.y;
        pts[4*tid+1] = make_float4(x, y, z, -0.5f * (x*x + y*y + z*z));
        x = b.z; y = b.w; z = c.x;
        pts[4*tid+2] = make_float4(x, y, z, -0.5f * (x*x + y*y + z*z));
        x = c.y; y = c.z; z = c.w;
        pts[4*tid+3] = make_float4(x, y, z, -0.5f * (x*x + y*y + z*z));
    }
    if (tid < 256) sW[tid] = tpw[tid];
    __syncthreads();

    const int q0 = nodeBase + wv * QPW;          // this wave's 4 query nodes
    const float4 P0 = pts[q0],   P1 = pts[q0+1];
    const float4 P2 = pts[q0+2], P3 = pts[q0+3];
    const float x0 = P0.x, y0 = P0.y, z0 = P0.z;
    const float x1 = P1.x, y1 = P1.y, z1 = P1.z;
    const float x2 = P2.x, y2 = P2.y, z2 = P2.z;
    const float x3 = P3.x, y3 = P3.y, z3 = P3.z;

    // ---- phase 1: 4 branchless per-lane top-2 ladders, one LDS read ----
    float b0 = -BIGF, s0 = -BIGF, b1 = -BIGF, s1 = -BIGF;
    float b2 = -BIGF, s2 = -BIGF, b3 = -BIGF, s3 = -BIGF;
    int bi0 = -1, si0 = -1, bi1 = -1, si1 = -1;
    int bi2 = -1, si2 = -1, bi3 = -1, si3 = -1;

    #pragma unroll 4
    for (int c = 0; c < NN / 64; ++c) {
        int j = lane + (c << 6);
        float4 P = pts[j];
        float d0 = fmaf(P.x, x0, fmaf(P.y, y0, fmaf(P.z, z0, P.w)));
        float d1 = fmaf(P.x, x1, fmaf(P.y, y1, fmaf(P.z, z1, P.w)));
        float d2 = fmaf(P.x, x2, fmaf(P.y, y2, fmaf(P.z, z2, P.w)));
        float d3 = fmaf(P.x, x3, fmaf(P.y, y3, fmaf(P.z, z3, P.w)));
        LADDER(d0, b0, bi0, s0, si0)
        LADDER(d1, b1, bi1, s1, si1)
        LADDER(d2, b2, bi2, s2, si2)
        LADDER(d3, b3, bi3, s3, si3)
    }

    // self wins its own column: demote it (per query)
    if (lane == ((q0  ) & 63) && bi0 == q0  ) { b0 = s0; bi0 = si0; s0 = -BIGF; si0 = -1; }
    if (lane == ((q0+1) & 63) && bi1 == q0+1) { b1 = s1; bi1 = si1; s1 = -BIGF; si1 = -1; }
    if (lane == ((q0+2) & 63) && bi2 == q0+2) { b2 = s2; bi2 = si2; s2 = -BIGF; si2 = -1; }
    if (lane == ((q0+3) & 63) && bi3 == q0+3) { b3 = s3; bi3 = si3; s3 = -BIGF; si3 = -1; }

    // ---- phase 2: 4 sequential extraction passes ----
    int selIdx = 0;                     // lane 16*q + r owns edge r of query q
    extract16(b0, bi0, s0, si0, x0, y0, z0, q0,   0,  pts, lane, selIdx);
    extract16(b1, bi1, s1, si1, x1, y1, z1, q0+1, 16, pts, lane, selIdx);
    extract16(b2, bi2, s2, si2, x2, y2, z2, q0+2, 32, pts, lane, selIdx);
    extract16(b3, bi3, s3, si3, x3, y3, z3, q0+3, 48, pts, lane, selIdx);

    // ---- epilogue: each lane computes its edge's 24 S-components once ----
    const int eq = lane >> 4;
    float xq = (eq & 2) ? ((eq & 1) ? x3 : x2) : ((eq & 1) ? x1 : x0);
    float yq = (eq & 2) ? ((eq & 1) ? y3 : y2) : ((eq & 1) ? y1 : y0);
    float zq = (eq & 2) ? ((eq & 1) ? z3 : z2) : ((eq & 1) ? z1 : z0);

    float4 P = pts[selIdx];
    float rx = P.x - xq, ry = P.y - yq, rz = P.z - zq;   // sender - receiver
    float dist = sqrtf(rx*rx + ry*ry + rz*rz);
    float inv  = 1.0f / (dist + 1e-8f);
    float hx = rx * inv, hy = ry * inv, hz = rz * inv;
    float cu = fminf(dist / 10.0f, 1.0f);
    float gg[8], ssum = 0.0f;
    #pragma unroll
    for (int v = 0; v < 8; ++v) {
        float d = cu - (float)v * (1.0f / 7.0f);
        gg[v] = expf(d * d * -32.0f);
        ssum += gg[v];
    }
    float is = 1.0f / ssum;
    float S[24];
    #pragma unroll
    for (int v = 0; v < 8; ++v) {
        float rbv = gg[v] * is;
        S[3*v]   = rbv * hx;
        S[3*v+1] = rbv * hy;
        S[3*v+2] = rbv * hz;
    }
    // sum the 16 edges within each query's 16-lane row (DPP, VALU-only)
    #pragma unroll
    for (int t = 0; t < 24; ++t) S[t] = row16_sum_dpp(S[t]);

    // W column held once in registers, reused for all 4 queries
    float wcol[8];
    #pragma unroll
    for (int v = 0; v < 8; ++v) wcol[v] = sW[32*v + (lane & 31)];

    const float scale = 0.036084391824351613f;   // 1/(16*sqrt(3))
    const float4 z4 = make_float4(0.f, 0.f, 0.f, 0.f);

    #pragma unroll
    for (int q = 0; q < QPW; ++q) {
        const int gq = batch * NN + q0 + q;
        float sg[24];
        #pragma unroll
        for (int t = 0; t < 24; ++t)
            sg[t] = __int_as_float(
                __builtin_amdgcn_readlane(__float_as_int(S[t]), 16 * q + 15));

        float* onode = out + (size_t)gq * 464;
        float4* o4 = (float4*)onode;
        if (lane < 16)       o4[lane] = z4;          // ch 0..63
        else if (lane < 36)  o4[lane + 24] = z4;     // ch 160..239

        if (lane < 32) {
            float a0 = 0.f, a1 = 0.f, a2 = 0.f;
            #pragma unroll
            for (int v = 0; v < 8; ++v) {
                a0 = fmaf(wcol[v], sg[3*v],   a0);
                a1 = fmaf(wcol[v], sg[3*v+1], a1);
                a2 = fmaf(wcol[v], sg[3*v+2], a2);
            }
            onode[64 + 3*lane]     = a0 * scale;
            onode[64 + 3*lane + 1] = a1 * scale;
            onode[64 + 3*lane + 2] = a2 * scale;
        }

        const int at = atypes[gq];
        const int rt = rtypes[gq];
        if (lane < 56) {
            float4 v = (lane < 28)
                ? ((const float4*)(aemb + 112*at))[lane]
                : ((const float4*)(remb + 112*rt))[lane - 28];
            o4[60 + lane] = v;
        }
    }
}

extern "C" void kernel_launch(void* const* d_in, const int* in_sizes, int n_in,
                              void* d_out, int out_size, void* d_ws, size_t ws_size,
                              hipStream_t stream)
{
    const float* coords = (const float*)d_in[0];
    const int*   at     = (const int*)  d_in[1];
    const int*   rt     = (const int*)  d_in[2];
    const float* tpw    = (const float*)d_in[3];
    const float* ae     = (const float*)d_in[4];
    const float* re     = (const float*)d_in[5];
    float* out = (float*)d_out;

    const int B = in_sizes[1] / NN;                  // 8
    dim3 grid(B * (NN / QPB));
    protein_enc_kernel<<<grid, BLOCK, 0, stream>>>(coords, at, rt, tpw, ae, re, out);
}